// Round 2
// baseline (143.066 us; speedup 1.0000x reference)
//
#include <hip/hip_runtime.h>

// WaveletLayer: db2 DWT -> gain -> IDWT -> ReLU, fused 6-tap stencil.
// v3: 4 quads per thread (strided, per-instruction coalesced), one 256-thread
// block per row (grid 4096). 4 independent float4 loads in flight per wave
// for memory-level parallelism; halo via cross-lane shuffles (v2 logic,
// verified); nontemporal float4 stores.

#define NN 4096
#define LL 2049
#define QUADS 1024   // float4 outputs per row
#define TPB 256
#define QPT 4        // quads per thread: TPB*QPT == QUADS

typedef float v4f __attribute__((ext_vector_type(4)));

__global__ __launch_bounds__(TPB) void wavelet_fused(const float* __restrict__ x,
                                                     const float* __restrict__ ker,
                                                     float* __restrict__ out) {
    const int row  = blockIdx.x;
    const int tid  = threadIdx.x;
    const int lane = tid & 63;

    // db2 decomposition taps
    const float lo0 = -0.12940952255126037f, lo1 = 0.22414386804185735f,
                lo2 =  0.8365163037378079f,  lo3 = 0.48296291314453416f;
    const float hi0 = -0.48296291314453416f, hi1 = 0.8365163037378079f,
                hi2 = -0.22414386804185737f, hi3 = -0.12940952255126037f;

    const v4f*   x4   = (const v4f*)(x + (size_t)row * NN);
    const float* krow = ker + (size_t)row * LL;

    // ---- issue all loads up front: 4 independent float4 + 8 ker dwords ----
    v4f   vc[QPT];
    float g0[QPT], g1[QPT];
    #pragma unroll
    for (int k = 0; k < QPT; ++k) {
        const int q = k * TPB + tid;
        vc[k] = x4[q];
    }
    #pragma unroll
    for (int k = 0; k < QPT; ++k) {
        const int q = k * TPB + tid;
        g0[k] = krow[2 * q];
        g1[k] = krow[2 * q + 1];
    }

    // wave-edge halo loads (predicated: only lanes 0/63 issue them)
    float ha[QPT], hb[QPT], hg[QPT];
    #pragma unroll
    for (int k = 0; k < QPT; ++k) {
        const int q = k * TPB + tid;
        ha[k] = 0.0f; hb[k] = 0.0f; hg[k] = 0.0f;
        if (lane == 0) {
            const v4f vp = x4[(q > 0) ? (q - 1) : 0];
            ha[k] = vp.z; hb[k] = vp.w;              // e0,e1 for lane 0
        } else if (lane == 63) {
            const v4f vn = x4[(q < QUADS - 1) ? (q + 1) : q];
            ha[k] = vn.x; hb[k] = vn.y;              // e6,e7 for lane 63
            hg[k] = krow[2 * q + 2];                 // g2 (2q+2 <= 2048, valid)
        }
    }

    v4f* out4 = (v4f*)(out + (size_t)row * NN);

    #pragma unroll
    for (int k = 0; k < QPT; ++k) {
        const int q = k * TPB + tid;

        // interior halo via cross-lane shuffles (lanes are consecutive q)
        float e0 = __shfl_up(vc[k].z, 1);    // prev.z
        float e1 = __shfl_up(vc[k].w, 1);    // prev.w
        float e6 = __shfl_down(vc[k].x, 1);  // next.x
        float e7 = __shfl_down(vc[k].y, 1);  // next.y
        float g2 = __shfl_down(g0[k], 1);    // g[2q+2] = next lane's g0

        if (lane == 0)  { e0 = ha[k]; e1 = hb[k]; }
        if (lane == 63) { e6 = ha[k]; e7 = hb[k]; g2 = hg[k]; }
        // symmetric-padding boundary overrides (verified mapping)
        if (q == 0)         { e0 = vc[k].y; e1 = vc[k].x; }  // X(-2)=x[1], X(-1)=x[0]
        if (q == QUADS - 1) { e6 = vc[k].w; e7 = vc[k].z; }  // X(4096)=x[4095], X(4097)=x[4094]

        const float e2 = vc[k].x, e3 = vc[k].y, e4 = vc[k].z, e5 = vc[k].w;

        // analysis
        const float cA0 = lo3 * e0 + lo2 * e1 + lo1 * e2 + lo0 * e3;
        const float cD0 = hi3 * e0 + hi2 * e1 + hi1 * e2 + hi0 * e3;
        const float cA1 = lo3 * e2 + lo2 * e3 + lo1 * e4 + lo0 * e5;
        const float cD1 = hi3 * e2 + hi2 * e3 + hi1 * e4 + hi0 * e5;
        const float cA2 = lo3 * e4 + lo2 * e5 + lo1 * e6 + lo0 * e7;
        const float cD2 = hi3 * e4 + hi2 * e5 + hi1 * e6 + hi0 * e7;

        const float A0 = g0[k] * cA0, D0 = g0[k] * cD0;
        const float A1 = g1[k] * cA1, D1 = g1[k] * cD1;
        const float A2 = g2 * cA2,    D2 = g2 * cD2;

        // synthesis
        float y0 = lo1 * A0 + lo3 * A1 + hi1 * D0 + hi3 * D1;
        float y1 = lo0 * A0 + lo2 * A1 + hi0 * D0 + hi2 * D1;
        float y2 = lo1 * A1 + lo3 * A2 + hi1 * D1 + hi3 * D2;
        float y3 = lo0 * A1 + lo2 * A2 + hi0 * D1 + hi2 * D2;

        v4f res;
        res.x = fmaxf(y0, 0.0f);
        res.y = fmaxf(y1, 0.0f);
        res.z = fmaxf(y2, 0.0f);
        res.w = fmaxf(y3, 0.0f);

        __builtin_nontemporal_store(res, out4 + q);
    }
}

extern "C" void kernel_launch(void* const* d_in, const int* in_sizes, int n_in,
                              void* d_out, int out_size, void* d_ws, size_t ws_size,
                              hipStream_t stream) {
    const float* x   = (const float*)d_in[0];
    const float* ker = (const float*)d_in[1];
    float* out = (float*)d_out;
    wavelet_fused<<<dim3(4096), dim3(TPB), 0, stream>>>(x, ker, out);
}

// Round 4
// 140.809 us; speedup vs baseline: 1.0160x; 1.0160x over previous
//
#include <hip/hip_runtime.h>

// WaveletLayer: db2 DWT -> gain -> IDWT -> ReLU, fused 6-tap stencil.
// v4 (resubmit after infra failure): persistent grid-stride sweep (G11):
// 2048 blocks x 256 thr = 8 WG/CU (32 waves/CU), each thread walks 8 quads
// at stride 512K quads so the whole grid sweeps x/ker/out front-to-back as
// one coherent stream (copy-benchmark access pattern). Per-quad body is the
// verified v2 form: 1 float4 x-load + shuffled halo + predicated edge loads,
// ker as one float2 load, nontemporal float4 store.

#define NN 4096
#define LL 2049
#define QUADS 1024            // float4 outputs per row
#define TPB 256
#define GRID 2048             // 8 WGs per CU on 256 CUs
#define TOTAL_QUADS (4096 * QUADS)      // 4194304
#define SWEEP (GRID * TPB)              // 524288 quads per sweep step
#define ITERS (TOTAL_QUADS / SWEEP)     // 8, exact

typedef float v4f __attribute__((ext_vector_type(4)));
typedef float v2f __attribute__((ext_vector_type(2)));

__global__ __launch_bounds__(TPB) void wavelet_fused(const float* __restrict__ x,
                                                     const float* __restrict__ ker,
                                                     float* __restrict__ out) {
    const int lane = threadIdx.x & 63;

    // db2 decomposition taps
    const float lo0 = -0.12940952255126037f, lo1 = 0.22414386804185735f,
                lo2 =  0.8365163037378079f,  lo3 = 0.48296291314453416f;
    const float hi0 = -0.48296291314453416f, hi1 = 0.8365163037378079f,
                hi2 = -0.22414386804185735f, hi3 = -0.12940952255126037f;

    int Q = blockIdx.x * TPB + threadIdx.x;   // global quad index

    #pragma unroll 1
    for (int it = 0; it < ITERS; ++it, Q += SWEEP) {
        const int row = Q >> 10;        // QUADS = 1024
        const int t   = Q & (QUADS - 1);

        const v4f*   x4   = (const v4f*)(x + (size_t)row * NN);
        const float* krow = ker + (size_t)row * LL;

        // own data: one float4 x-load + one float2 ker load
        const v4f vc  = x4[t];
        const v2f g01 = *(const v2f*)(krow + 2 * t);   // g[2t], g[2t+1]
        const float g0 = g01.x, g1 = g01.y;

        // wave-edge halo (predicated: only lanes 0/63 issue loads)
        float ha = 0.0f, hb = 0.0f, hg = 0.0f;
        if (lane == 0) {
            const v4f vp = x4[(t > 0) ? (t - 1) : 0];
            ha = vp.z; hb = vp.w;                     // e0,e1 for lane 0
        } else if (lane == 63) {
            const v4f vn = x4[(t < QUADS - 1) ? (t + 1) : t];
            ha = vn.x; hb = vn.y;                     // e6,e7 for lane 63
            hg = krow[2 * t + 2];                     // g2 (2t+2 <= 2048, valid)
        }

        // interior halo via cross-lane shuffles (lanes are consecutive Q;
        // cross-row leakage is fixed by the t==0 / t==QUADS-1 overrides)
        float e0 = __shfl_up(vc.z, 1);    // prev.z
        float e1 = __shfl_up(vc.w, 1);    // prev.w
        float e6 = __shfl_down(vc.x, 1);  // next.x
        float e7 = __shfl_down(vc.y, 1);  // next.y
        float g2 = __shfl_down(g0, 1);    // g[2t+2] = next lane's g0

        if (lane == 0)  { e0 = ha; e1 = hb; }
        if (lane == 63) { e6 = ha; e7 = hb; g2 = hg; }
        // symmetric-padding boundary overrides (verified mapping)
        if (t == 0)         { e0 = vc.y; e1 = vc.x; }  // X(-2)=x[1], X(-1)=x[0]
        if (t == QUADS - 1) { e6 = vc.w; e7 = vc.z; }  // X(4096)=x[4095], X(4097)=x[4094]

        const float e2 = vc.x, e3 = vc.y, e4 = vc.z, e5 = vc.w;

        // analysis: cA[j] = lo3*X(2j-2)+lo2*X(2j-1)+lo1*X(2j)+lo0*X(2j+1)
        const float cA0 = lo3 * e0 + lo2 * e1 + lo1 * e2 + lo0 * e3;
        const float cD0 = hi3 * e0 + hi2 * e1 + hi1 * e2 + hi0 * e3;
        const float cA1 = lo3 * e2 + lo2 * e3 + lo1 * e4 + lo0 * e5;
        const float cD1 = hi3 * e2 + hi2 * e3 + hi1 * e4 + hi0 * e5;
        const float cA2 = lo3 * e4 + lo2 * e5 + lo1 * e6 + lo0 * e7;
        const float cD2 = hi3 * e4 + hi2 * e5 + hi1 * e6 + hi0 * e7;

        const float A0 = g0 * cA0, D0 = g0 * cD0;
        const float A1 = g1 * cA1, D1 = g1 * cD1;
        const float A2 = g2 * cA2, D2 = g2 * cD2;

        // synthesis: y[2m]   = lo1*A[m]+lo3*A[m+1]+hi1*D[m]+hi3*D[m+1]
        //            y[2m+1] = lo0*A[m]+lo2*A[m+1]+hi0*D[m]+hi2*D[m+1]
        float y0 = lo1 * A0 + lo3 * A1 + hi1 * D0 + hi3 * D1;
        float y1 = lo0 * A0 + lo2 * A1 + hi0 * D0 + hi2 * D1;
        float y2 = lo1 * A1 + lo3 * A2 + hi1 * D1 + hi3 * D2;
        float y3 = lo0 * A1 + lo2 * A2 + hi0 * D1 + hi2 * D2;

        v4f res;
        res.x = fmaxf(y0, 0.0f);
        res.y = fmaxf(y1, 0.0f);
        res.z = fmaxf(y2, 0.0f);
        res.w = fmaxf(y3, 0.0f);

        v4f* out4 = (v4f*)(out + (size_t)row * NN);
        __builtin_nontemporal_store(res, out4 + t);
    }
}

extern "C" void kernel_launch(void* const* d_in, const int* in_sizes, int n_in,
                              void* d_out, int out_size, void* d_ws, size_t ws_size,
                              hipStream_t stream) {
    const float* x   = (const float*)d_in[0];
    const float* ker = (const float*)d_in[1];
    float* out = (float*)d_out;
    wavelet_fused<<<dim3(GRID), dim3(TPB), 0, stream>>>(x, ker, out);
}